// Round 1
// 177.365 us; speedup vs baseline: 1.0021x; 1.0021x over previous
//
#include <hip/hip_runtime.h>

// Problem constants (fixed by setup_inputs)
constexpr int kB  = 4;
constexpr int kNp = 8192;
constexpr int kNq = 2048;
constexpr int kK  = 32;   // max samples per query
constexpr float kR2 = (float)(0.2 * 0.2);   // matches numpy f32(radius*radius)

typedef float v4f __attribute__((ext_vector_type(4)));
typedef int   v4i __attribute__((ext_vector_type(4)));

// ---------------------------------------------------------------------------
// Kernel A: coords [B][Np][3] -> SoA cb3 [B][3][Np]. (proven; ~4 us)
// ---------------------------------------------------------------------------
__global__ __launch_bounds__(256) void coords_soa_kernel(
    const float* __restrict__ coords, float* __restrict__ cb3)
{
    const int t = blockIdx.x * 256 + threadIdx.x;   // 0 .. B*Np-1
    const int b = t >> 13;                          // / Np
    const int p = t & (kNp - 1);
    const float x = coords[(size_t)t * 3 + 0];
    const float y = coords[(size_t)t * 3 + 1];
    const float z = coords[(size_t)t * 3 + 2];
    float* o = cb3 + (size_t)b * 3 * kNp;
    o[0 * kNp + p] = x;
    o[1 * kNp + p] = y;
    o[2 * kNp + p] = z;
}

// ---------------------------------------------------------------------------
// Kernel B: ball query, one wave per query. NEW vs prior round: next-chunk
// loads are issued unconditionally at the TOP of each iteration (clamped
// in-bounds) and registers rotated before the early-exit, so the L2 load
// latency (~200-300 cy) is removed from the loop-carried chain
// (load -> ballot -> popcount -> branch -> load). Index selection and
// arithmetic are bit-identical to the verified kernel.
// ---------------------------------------------------------------------------
__global__ __launch_bounds__(256) void ball_query_kernel(
    const float* __restrict__ cb3,      // [B][3][Np]
    const float* __restrict__ queries,  // [B][Nq][3]
    int* __restrict__ idxs,             // [B*Nq][K] (resolved, fill applied)
    float* __restrict__ out)            // full output tensor
{
    const int wave = (int)((blockIdx.x * blockDim.x + threadIdx.x) >> 6);
    const int lane = threadIdx.x & 63;
    const int w    = threadIdx.x >> 6;          // wave within block (0..3)
    const int b    = wave >> 11;                // / Nq
    const int q    = wave & (kNq - 1);

    const float qx = queries[(b * kNq + q) * 3 + 0];
    const float qy = queries[(b * kNq + q) * 3 + 1];
    const float qz = queries[(b * kNq + q) * 3 + 2];

    const float* __restrict__ cbx = cb3 + (size_t)b * 3 * kNp;
    const float* __restrict__ cby = cbx + kNp;
    const float* __restrict__ cbz = cby + kNp;
    const v4f* __restrict__ cbx4 = (const v4f*)cbx;
    const v4f* __restrict__ cby4 = (const v4f*)cby;
    const v4f* __restrict__ cbz4 = (const v4f*)cbz;

    __shared__ int s_idx[4][kK];   // per-wave private region; no barrier needed

    const unsigned long long lt = (1ull << lane) - 1ull;
    int cnt = 0;

    // prologue: load chunk 0
    v4f X = cbx4[lane];
    v4f Y = cby4[lane];
    v4f Z = cbz4[lane];

    for (int base = 0; base < kNp; base += 256) {
        // prefetch chunk base+256 (clamped: overshoot re-reads chunk 0,
        // always in-bounds; values unused when we exit or wrap)
        const int nvi = (base + 256 < kNp) ? (((base + 256) >> 2) + lane) : lane;
        const v4f Xn = cbx4[nvi];
        const v4f Yn = cby4[nvi];
        const v4f Zn = cbz4[nvi];

        bool in[4];
        unsigned long long m[4];
#pragma unroll
        for (int j = 0; j < 4; ++j) {
            // exact f32 per-op arithmetic (no fma contraction) to match numpy
            const float dx = __fsub_rn(qx, X[j]);
            const float dy = __fsub_rn(qy, Y[j]);
            const float dz = __fsub_rn(qz, Z[j]);
            const float d2 = __fadd_rn(
                __fadd_rn(__fmul_rn(dx, dx), __fmul_rn(dy, dy)),
                __fmul_rn(dz, dz));
            in[j] = d2 < kR2;
            m[j] = __ballot(in[j]);
        }

        // point index = base + 4*lane + j (lane-major)
        int pre = cnt + __popcll(m[0] & lt) + __popcll(m[1] & lt)
                      + __popcll(m[2] & lt) + __popcll(m[3] & lt);
        int local = 0;
#pragma unroll
        for (int j = 0; j < 4; ++j) {
            if (in[j]) {
                const int slot = pre + local;
                if (slot < kK) s_idx[w][slot] = base + 4 * lane + j;
                ++local;
            }
        }
        cnt += __popcll(m[0]) + __popcll(m[1])
             + __popcll(m[2]) + __popcll(m[3]);     // wave-uniform

        // rotate BEFORE the break so the prefetched values are live across
        // the backedge (keeps the loads hoisted to iteration top)
        X = Xn; Y = Yn; Z = Zn;
        if (cnt >= kK) break;                       // uniform branch
    }

    if (lane < kK) {
        int v;
        if (cnt == 0)        v = 0;
        else if (lane < cnt) v = s_idx[w][lane];
        else                 v = s_idx[w][0];       // fill with first valid
        idxs[(size_t)wave * kK + lane] = v;

        // centered-coords output channels 0..2 of grouped_features
        // (write-once output stream: non-temporal, keep L2 for cb3/idxs)
        const int k = lane;
        float* gf = out + ((size_t)(b * 67) * kNq + q) * kK + k;
        __builtin_nontemporal_store(__fsub_rn(cbx[v], qx), gf + (size_t)0 * kNq * kK);
        __builtin_nontemporal_store(__fsub_rn(cby[v], qy), gf + (size_t)1 * kNq * kK);
        __builtin_nontemporal_store(__fsub_rn(cbz[v], qz), gf + (size_t)2 * kNq * kK);
    }
}

// ---------------------------------------------------------------------------
// Kernel C: scatter-free gather. NEW vs prior round:
//  (a) non-temporal stores for the 131 MB output stream and non-temporal
//      loads for the once-read row staging -> the idx array (256 KB/batch,
//      re-read by 128 blocks/batch) stays L2-resident instead of being
//      evicted by the write stream;
//  (b) each (b, channel) is split into 2 query-halves -> 1024 blocks,
//      4 blocks/CU (128 KB LDS of 160 KB), doubling latency-hiding waves.
// ---------------------------------------------------------------------------
__global__ __launch_bounds__(256) void gather_kernel(
    const float* __restrict__ feat,   // [B][64][Np]
    const float* __restrict__ temb,   // [B][64][Np]
    const int*   __restrict__ idxs,   // [B*Nq][K] resolved
    float* __restrict__ out)
{
    const int blk = blockIdx.x;        // 0 .. 1023
    const int seg = blk & 1;           // query half
    const int bc  = blk >> 1;          // 0 .. 511
    const int b   = bc >> 7;
    const int j   = bc & 127;          // 0..63 feat, 64..127 temb

    const float* src;
    float* dst;
    if (j < 64) {
        src = feat + ((size_t)b * 64 + j) * kNp;
        dst = out + (size_t)(b * 67 + 3 + j) * (kNq * kK);
    } else {
        src = temb + ((size_t)b * 64 + (j - 64)) * kNp;
        dst = out + (size_t)kB * 67 * kNq * kK
                  + (size_t)(b * 64 + (j - 64)) * (kNq * kK);
    }

    __shared__ float row[kNp];         // 32 KB
    {
        const v4f* s4 = (const v4f*)src;
        v4f* r4 = (v4f*)row;
#pragma unroll
        for (int i = 0; i < kNp / 4 / 256; ++i)     // 8 iters
            r4[i * 256 + threadIdx.x] =
                __builtin_nontemporal_load(s4 + i * 256 + threadIdx.x);
    }
    __syncthreads();

    constexpr int total4 = kNq * kK / 4;            // 16384
    constexpr int seg4   = total4 / 2;              // 8192 per half
    const v4i* id4 = (const v4i*)(idxs + (size_t)b * kNq * kK) + seg * seg4;
    v4f* d4 = (v4f*)dst + seg * seg4;
#pragma unroll 4
    for (int e = threadIdx.x; e < seg4; e += 256) {
        const v4i id = id4[e];
        v4f v;
        v.x = row[id.x];
        v.y = row[id.y];
        v.z = row[id.z];
        v.w = row[id.w];
        __builtin_nontemporal_store(v, d4 + e);
    }
}

// ---------------------------------------------------------------------------
extern "C" void kernel_launch(void* const* d_in, const int* in_sizes, int n_in,
                              void* d_out, int out_size, void* d_ws, size_t ws_size,
                              hipStream_t stream) {
    const float* coords  = (const float*)d_in[0];  // [B,Np,3]
    const float* feats   = (const float*)d_in[1];  // [B,64,Np]
    const float* temb    = (const float*)d_in[2];  // [B,64,Np]
    const float* queries = (const float*)d_in[3];  // [B,Nq,3]
    float* out = (float*)d_out;

    int*   idxs = (int*)d_ws;                                          // 1 MB
    float* cb3  = (float*)((char*)d_ws + (size_t)kB * kNq * kK * 4);   // 384 KB

    coords_soa_kernel<<<kB * kNp / 256, 256, 0, stream>>>(coords, cb3);
    ball_query_kernel<<<kB * kNq / 4, 256, 0, stream>>>(cb3, queries, idxs, out);
    gather_kernel<<<kB * 128 * 2, 256, 0, stream>>>(feats, temb, idxs, out);
}